// Round 5
// baseline (81.909 us; speedup 1.0000x reference)
//
#include <hip/hip_runtime.h>
#include <stdint.h>

typedef float    f32x4  __attribute__((ext_vector_type(4)));
typedef __bf16   bf16x8 __attribute__((ext_vector_type(8)));
typedef uint32_t u32x4  __attribute__((ext_vector_type(4)));
typedef unsigned short u16x4 __attribute__((ext_vector_type(4)));

#define AS1 __attribute__((address_space(1)))
#define AS3 __attribute__((address_space(3)))

__device__ __forceinline__ unsigned short f2bf_bits(float f) {
  uint32_t u = __builtin_bit_cast(uint32_t, f);
  u += 0x7fffu + ((u >> 16) & 1u);      // RNE to bf16
  return (unsigned short)(u >> 16);
}

// ---------------- kernel 0: At[col][k] (bf16) = A[k][col] ----------------
// A: [256][1024] f32  ->  At: [1024][256] bf16 (in d_ws)
__global__ void k_transpose_cvt(const float* __restrict__ A,
                                unsigned short* __restrict__ At) {
  int n = blockIdx.x * blockDim.x + threadIdx.x;  // 65536 threads
  int o = n << 2;                                 // 4 elements per thread
  int col = o >> 8;
  int k   = o & 255;
  u16x4 v;
#pragma unroll
  for (int j = 0; j < 4; ++j) v[j] = f2bf_bits(A[(size_t)(k + j) * 1024 + col]);
  *reinterpret_cast<u16x4*>(At + o) = v;          // coalesced write
}

// ---------------- kernel 1: fused GEMM + silu rowsum + zero-fill + diag ----
// x: [65536][256] f32, At: [1024][256] bf16, out: [1024][256][256] f32
// Block: 256 threads (4 waves), BM = 128 rows. Grid: 512 blocks.
// Pipeline: 4 LDS buffers, 2-tile-deep global_load_lds prefetch, ONE raw
// s_barrier per tile with counted s_waitcnt vmcnt(8) — zero-fill stores and
// prefetch loads stay in flight across barriers (never drained in the loop).
// Epilogue: single vmcnt(0)+barrier, then diagonal writes.
__launch_bounds__(256, 2)
__global__ void k_gemm_fused(const float* __restrict__ x,
                             const unsigned short* __restrict__ At,
                             float* __restrict__ out) {
  __shared__ alignas(16) char lds[4][8192];

  const int tid  = threadIdx.x;
  const int lane = tid & 63;
  const int w    = tid >> 6;          // wave 0..3
  const int bIdx = blockIdx.x;        // 0..511
  const int brow = bIdx * 128;

  const int col = lane & 15;          // A-frag row / B-frag col / C col
  const int hi  = lane >> 4;          // k-subblock select

  // staging: LDS linear chunk p (16B) <- global byte (p ^ swz(p)); swz is an
  // involution on bits 4..6 keyed by bits 9..11, so the ds_read side applies
  // the same XOR and gets conflict-free b128 reads.
  uint32_t p0  = (uint32_t)(w * 2048 + lane * 16);
  uint32_t so0 = p0 ^ (((p0 >> 9) & 7u) << 4);
  uint32_t p1  = p0 + 1024u;
  uint32_t so1 = p1 ^ (((p1 >> 9) & 7u) << 4);

  // ---- prefetch tiles 0,1 into buffers 0,1 (complete during x-load phase) --
  {
    const char* t0 = (const char*)At;
    const char* t1 = (const char*)At + 8192;
    __builtin_amdgcn_global_load_lds((const AS1 uint32_t*)(t0 + so0),
                                     (AS3 uint32_t*)(lds[0] + w * 2048), 16, 0, 0);
    __builtin_amdgcn_global_load_lds((const AS1 uint32_t*)(t0 + so1),
                                     (AS3 uint32_t*)(lds[0] + w * 2048 + 1024), 16, 0, 0);
    __builtin_amdgcn_global_load_lds((const AS1 uint32_t*)(t1 + so0),
                                     (AS3 uint32_t*)(lds[1] + w * 2048), 16, 0, 0);
    __builtin_amdgcn_global_load_lds((const AS1 uint32_t*)(t1 + so1),
                                     (AS3 uint32_t*)(lds[1] + w * 2048 + 1024), 16, 0, 0);
  }
  __builtin_amdgcn_sched_barrier(0);   // keep x loads below the prefetches

  // ---- x fragments in registers: rows w*32 + rg*16 + col, k = s*32 + hi*8 --
  bf16x8 xf[2][8];
#pragma unroll
  for (int rg = 0; rg < 2; ++rg) {
    const float* xr = x + (size_t)(brow + w * 32 + rg * 16 + col) * 256;
#pragma unroll
    for (int s = 0; s < 8; ++s) {
      f32x4 a = __builtin_nontemporal_load(
          reinterpret_cast<const f32x4*>(xr + s * 32 + hi * 8));
      f32x4 b = __builtin_nontemporal_load(
          reinterpret_cast<const f32x4*>(xr + s * 32 + hi * 8 + 4));
      bf16x8 f;
      f[0] = (__bf16)a[0]; f[1] = (__bf16)a[1];
      f[2] = (__bf16)a[2]; f[3] = (__bf16)a[3];
      f[4] = (__bf16)b[0]; f[5] = (__bf16)b[1];
      f[6] = (__bf16)b[2]; f[7] = (__bf16)b[3];
      xf[rg][s] = f;
    }
  }
  // drain prologue completely -> loop's counted vmcnt sees only loop ops
  asm volatile("s_waitcnt vmcnt(0)" ::: "memory");

  // B-frag read base: element (col, k= s*32 + hi*8) -> byte col*512+s*64+hi*16,
  // XOR (col&7)<<4.  Fields are disjoint bits, so addr(s) = rbase ^ (s<<6).
  uint32_t rbase = ((uint32_t)(col * 512 + hi * 16)) ^ ((uint32_t)(col & 7) << 4);

  float sums[2][4] = {{0.f, 0.f, 0.f, 0.f}, {0.f, 0.f, 0.f, 0.f}};
  float* outblk = out + (size_t)bIdx * 131072;   // block's exclusive 512KB
  const f32x4 z4 = {0.f, 0.f, 0.f, 0.f};

  for (int tile = 0; tile < 64; ++tile) {
    // prefetch tile+2 (wrapped: keeps per-iter vmem issue pattern uniform so
    // vmcnt(8) is valid for every iteration; wrap stages are harmless)
    {
      int pt = (tile + 2) & 63;
      const char* tsrc = (const char*)At + (size_t)pt * 8192;
      char* dst = lds[(tile + 2) & 3] + w * 2048;
      __builtin_amdgcn_global_load_lds((const AS1 uint32_t*)(tsrc + so0),
                                       (AS3 uint32_t*)dst, 16, 0, 0);
      __builtin_amdgcn_global_load_lds((const AS1 uint32_t*)(tsrc + so1),
                                       (AS3 uint32_t*)(dst + 1024), 16, 0, 0);
    }
    // zero-fill 2 float4 of this block's out region (stays in flight)
    float* zp = outblk + tile * 2048 + (tid << 2);
    __builtin_nontemporal_store(z4, reinterpret_cast<f32x4*>(zp));
    __builtin_nontemporal_store(z4, reinterpret_cast<f32x4*>(zp + 1024));

    // wait: tile's loads complete (issued 2 iters ago; 8 younger vmem ops =
    // 2 prefetch loads + 2 stores from this iter + same from previous iter
    // may remain in flight), then cross-wave barrier. Fused in one asm so
    // nothing is scheduled between the wait and the barrier.
    asm volatile("s_waitcnt vmcnt(8)\n\ts_barrier" ::: "memory");

    const char* buf = lds[tile & 3];
    bf16x8 bfr[8];
#pragma unroll
    for (int s = 0; s < 8; ++s) {
      uint32_t addr = rbase ^ ((uint32_t)s << 6);
      bfr[s] = __builtin_bit_cast(
          bf16x8, *reinterpret_cast<const u32x4*>(buf + addr));
    }
    f32x4 acc[2] = {{0.f, 0.f, 0.f, 0.f}, {0.f, 0.f, 0.f, 0.f}};
#pragma unroll
    for (int s = 0; s < 8; ++s) {
      acc[0] = __builtin_amdgcn_mfma_f32_16x16x32_bf16(xf[0][s], bfr[s], acc[0], 0, 0, 0);
      acc[1] = __builtin_amdgcn_mfma_f32_16x16x32_bf16(xf[1][s], bfr[s], acc[1], 0, 0, 0);
    }
#pragma unroll
    for (int rg = 0; rg < 2; ++rg)
#pragma unroll
      for (int j = 0; j < 4; ++j) {
        float z = acc[rg][j];
        float sig = __builtin_amdgcn_rcpf(1.0f + __expf(-z));
        sums[rg][j] += z * sig;
      }
    // no second barrier: with 4 buffers the next write to this buffer is
    // issued 2 iterations (2 barriers) later — read-vs-write race impossible.
  }

  // drain ALL stores (zero-fills) + cross-wave sync before diagonal writes
  asm volatile("s_waitcnt vmcnt(0)\n\ts_barrier" ::: "memory");

  // ---- reduce over the 16 column-lanes (C layout: col = lane&15) ----
#pragma unroll
  for (int rg = 0; rg < 2; ++rg)
#pragma unroll
    for (int j = 0; j < 4; ++j) {
      float v = sums[rg][j];
      v += __shfl_xor(v, 1, 64);
      v += __shfl_xor(v, 2, 64);
      v += __shfl_xor(v, 4, 64);
      v += __shfl_xor(v, 8, 64);
      sums[rg][j] = v;
    }

  // block owns groups 2*bIdx, 2*bIdx+1 exclusively -> no inter-block hazard.
  if (col == 0) {
#pragma unroll
    for (int rg = 0; rg < 2; ++rg)
#pragma unroll
      for (int j = 0; j < 4; ++j) {
        int rb_ = brow + w * 32 + rg * 16 + hi * 4 + j;  // global row (= g*64+c)
        int g = rb_ >> 6;
        int c = rb_ & 63;
        float s = sums[rg][j];
        float* og = out + (size_t)g * 65536;
        og[(2 * c) * 256 + 128 + 2 * c]     =  s;   // out[g, i, 128+i], i=2c
        og[(2 * c + 1) * 256 + 129 + 2 * c] =  s;   // i=2c+1
        og[(128 + 2 * c) * 256 + 2 * c]     = -s;   // out[g, 128+i, i]
        og[(129 + 2 * c) * 256 + 2 * c + 1] = -s;
      }
  }
}

extern "C" void kernel_launch(void* const* d_in, const int* in_sizes, int n_in,
                              void* d_out, int out_size, void* d_ws, size_t ws_size,
                              hipStream_t stream) {
  const float* x = (const float*)d_in[0];   // [65536, 256]
  const float* A = (const float*)d_in[1];   // [256, 1024]
  float* out = (float*)d_out;               // [1024, 256, 256]
  unsigned short* At = (unsigned short*)d_ws;  // 512 KB bf16 transposed weights

  k_transpose_cvt<<<256, 256, 0, stream>>>(A, At);
  k_gemm_fused<<<512, 256, 0, stream>>>(x, At, out);
}